// Round 1
// baseline (446.362 us; speedup 1.0000x reference)
//
#include <hip/hip_runtime.h>
#include <hip/hip_bf16.h>
#include <stdint.h>

#define DD 4096
#define NPAIR 4096
#define NQUERY 4096

typedef __attribute__((ext_vector_type(4))) float f32x4;
typedef __attribute__((ext_vector_type(8))) short short8;
typedef __attribute__((ext_vector_type(8))) __bf16 bf16x8;

static __device__ __forceinline__ unsigned short f32_to_bf16_rn(float f) {
    unsigned int u = __float_as_uint(f);
    u += 0x7fffu + ((u >> 16) & 1u);
    return (unsigned short)(u >> 16);
}

// async global->LDS, 16B per lane. lds pointer must be wave-uniform.
static __device__ __forceinline__ void gload_lds16(const void* g, void* lds) {
    unsigned int lo = (unsigned int)(unsigned long long)(uintptr_t)lds;
    __builtin_amdgcn_global_load_lds(
        (const __attribute__((address_space(1))) unsigned int*)(uintptr_t)g,
        (__attribute__((address_space(3))) unsigned int*)lo,
        16, 0, 0);
}

static __device__ __forceinline__ f32x4 mfma16x16x32(short8 a, short8 b, f32x4 c) {
    return __builtin_amdgcn_mfma_f32_16x16x32_bf16(
        __builtin_bit_cast(bf16x8, a), __builtin_bit_cast(bf16x8, b), c, 0, 0, 0);
}

// in [R][C] f32 -> out [C][R] bf16 (transpose + convert). R,C multiples of 64.
__global__ void transpose_cvt_kernel(const float* __restrict__ in,
                                     unsigned short* __restrict__ out,
                                     int R, int C) {
    __shared__ float tile[64][65];
    const int t = (int)threadIdx.x;           // 0..255
    const int r0 = (int)blockIdx.y * 64;
    const int c0 = (int)blockIdx.x * 64;
    #pragma unroll
    for (int q = 0; q < 16; ++q) {
        int lin = q * 256 + t;
        int row = lin >> 6, col = lin & 63;
        tile[row][col] = in[(size_t)(r0 + row) * C + (c0 + col)];
    }
    __syncthreads();
    #pragma unroll
    for (int q = 0; q < 16; ++q) {
        int lin = q * 256 + t;
        int orow = lin >> 6, ocol = lin & 63; // orow = original col, ocol = original row
        out[(size_t)(c0 + orow) * R + (r0 + ocol)] = f32_to_bf16_rn(tile[ocol][orow]);
    }
}

// flat f32 -> bf16 convert, 4 elems/thread
__global__ void cvt_kernel(const float* __restrict__ in,
                           unsigned short* __restrict__ out, int n4) {
    int i = (int)(blockIdx.x * blockDim.x + threadIdx.x);
    if (i >= n4) return;
    float4 v = ((const float4*)in)[i];
    ushort4 o = make_ushort4(f32_to_bf16_rn(v.x), f32_to_bf16_rn(v.y),
                             f32_to_bf16_rn(v.z), f32_to_bf16_rn(v.w));
    ((ushort4*)out)[i] = o;
}

// Mcirc[p][n] = bf16(memory[(p+n) & (D-1)]), one block per row p
__global__ void mcirc_kernel(const float* __restrict__ memv,
                             unsigned short* __restrict__ mc) {
    __shared__ unsigned short mb[DD];
    const int t = (int)threadIdx.x;           // 0..255
    for (int q = t; q < DD; q += 256) mb[q] = f32_to_bf16_rn(memv[q]);
    __syncthreads();
    const int p = (int)blockIdx.x;
    unsigned short* row = mc + (size_t)p * DD;
    #pragma unroll
    for (int it = 0; it < 4; ++it) {
        int n = (t + it * 256) * 4;
        ushort4 o = make_ushort4(mb[(p + n) & (DD - 1)],
                                 mb[(p + n + 1) & (DD - 1)],
                                 mb[(p + n + 2) & (DD - 1)],
                                 mb[(p + n + 3) & (DD - 1)]);
        ((ushort4*)row)[n >> 2] = o;
    }
}

// C[m][n] = sum_k A[m][k] * B[n][k];  A:[M][K] bf16, B:[N][K] bf16 (row-major)
// EPI==0: write C (f32) to Cout[m*N+n]
// EPI==1: reduce anti-diagonals: atomicAdd memv[(m+n) & (DD-1)] += C[m][n]
template <int EPI>
__global__ __launch_bounds__(256, 2) void gemm_bt(
    const unsigned short* __restrict__ A, const unsigned short* __restrict__ B,
    float* __restrict__ Cout, float* __restrict__ memv, int N, int K) {
    __shared__ unsigned short As[128 * 32];   // [128 rows][32 k] bf16
    __shared__ unsigned short Bs[128 * 32];
    const int t = (int)threadIdx.x;
    const int l = t & 63;
    const int w = t >> 6;                     // wave 0..3
    const int wr = w >> 1, wc = w & 1;        // 2x2 wave grid, each 64x64
    const int m0 = (int)blockIdx.y * 128;
    const int n0 = (int)blockIdx.x * 128;

    f32x4 acc[4][4];
    #pragma unroll
    for (int i = 0; i < 4; ++i)
        #pragma unroll
        for (int j = 0; j < 4; ++j)
            acc[i][j] = (f32x4){0.f, 0.f, 0.f, 0.f};

    const int srow = t >> 2;                  // staging row 0..63
    const int scol = (t & 3) * 8;             // staging k-offset
    const unsigned short* Ag0 = A + (size_t)(m0 + srow) * K + scol;
    const unsigned short* Ag1 = A + (size_t)(m0 + 64 + srow) * K + scol;
    const unsigned short* Bg0 = B + (size_t)(n0 + srow) * K + scol;
    const unsigned short* Bg1 = B + (size_t)(n0 + 64 + srow) * K + scol;
    unsigned short* AsW = As + w * 512;       // wave-uniform LDS base (elements)
    unsigned short* BsW = Bs + w * 512;
    const int fr = l & 15;
    const int fq = l >> 4;

    for (int k0 = 0; k0 < K; k0 += 32) {
        __syncthreads();
        gload_lds16(Ag0 + k0, AsW);
        gload_lds16(Ag1 + k0, AsW + 2048);
        gload_lds16(Bg0 + k0, BsW);
        gload_lds16(Bg1 + k0, BsW + 2048);
        __syncthreads();
        short8 af[4], bfv[4];
        #pragma unroll
        for (int mi = 0; mi < 4; ++mi)
            af[mi] = *(const short8*)(As + (wr * 64 + mi * 16 + fr) * 32 + fq * 8);
        #pragma unroll
        for (int ni = 0; ni < 4; ++ni)
            bfv[ni] = *(const short8*)(Bs + (wc * 64 + ni * 16 + fr) * 32 + fq * 8);
        #pragma unroll
        for (int mi = 0; mi < 4; ++mi)
            #pragma unroll
            for (int ni = 0; ni < 4; ++ni)
                acc[mi][ni] = mfma16x16x32(af[mi], bfv[ni], acc[mi][ni]);
    }

    if constexpr (EPI == 0) {
        #pragma unroll
        for (int mi = 0; mi < 4; ++mi) {
            const int mrow = m0 + wr * 64 + mi * 16 + fq * 4;
            #pragma unroll
            for (int j = 0; j < 4; ++j) {
                #pragma unroll
                for (int ni = 0; ni < 4; ++ni) {
                    Cout[(size_t)(mrow + j) * N + (n0 + wc * 64 + ni * 16 + fr)] =
                        acc[mi][ni][j];
                }
            }
        }
    } else {
        __shared__ float bins[256];
        bins[t] = 0.f;
        __syncthreads();
        #pragma unroll
        for (int mi = 0; mi < 4; ++mi)
            #pragma unroll
            for (int ni = 0; ni < 4; ++ni)
                #pragma unroll
                for (int j = 0; j < 4; ++j) {
                    int ml = wr * 64 + mi * 16 + fq * 4 + j;
                    int nl = wc * 64 + ni * 16 + fr;
                    atomicAdd(&bins[ml + nl], acc[mi][ni][j]);
                }
        __syncthreads();
        atomicAdd(&memv[(m0 + n0 + t) & (DD - 1)], bins[t]);
    }
}

extern "C" void kernel_launch(void* const* d_in, const int* in_sizes, int n_in,
                              void* d_out, int out_size, void* d_ws, size_t ws_size,
                              hipStream_t stream) {
    const float* keys    = (const float*)d_in[0];
    const float* values  = (const float*)d_in[1];
    const float* queries = (const float*)d_in[2];
    float* out = (float*)d_out;
    char* ws = (char*)d_ws;

    unsigned short* A1 = (unsigned short*)ws;                          // 32MB: keys^T bf16, later queries bf16
    unsigned short* Bt = (unsigned short*)(ws + (size_t)(32 << 20));   // 32MB: values^T bf16, later Mcirc
    float* memv = (float*)(ws + (size_t)(64 << 20));                   // 16KB: memory vector

    hipMemsetAsync(memv, 0, DD * sizeof(float), stream);

    dim3 tgrid(DD / 64, NPAIR / 64);
    transpose_cvt_kernel<<<tgrid, 256, 0, stream>>>(keys, A1, NPAIR, DD);
    transpose_cvt_kernel<<<tgrid, 256, 0, stream>>>(values, Bt, NPAIR, DD);

    dim3 ggrid(DD / 128, DD / 128);
    gemm_bt<1><<<ggrid, 256, 0, stream>>>(A1, Bt, nullptr, memv, DD, NPAIR);

    mcirc_kernel<<<DD, 256, 0, stream>>>(memv, Bt);

    cvt_kernel<<<(NQUERY * DD / 4) / 256, 256, 0, stream>>>(queries, A1, NQUERY * DD / 4);

    gemm_bt<0><<<ggrid, 256, 0, stream>>>(A1, Bt, out, nullptr, DD, DD);
}

// Round 2
// 375.568 us; speedup vs baseline: 1.1885x; 1.1885x over previous
//
#include <hip/hip_runtime.h>
#include <hip/hip_bf16.h>
#include <stdint.h>

#define DD 4096
#define NPAIR 4096
#define NQUERY 4096
#define NT 64   // K / 64

typedef __attribute__((ext_vector_type(4))) float f32x4;
typedef __attribute__((ext_vector_type(8))) short short8;
typedef __attribute__((ext_vector_type(8))) __bf16 bf16x8;

static __device__ __forceinline__ unsigned short f32_to_bf16_rn(float f) {
    unsigned int u = __float_as_uint(f);
    u += 0x7fffu + ((u >> 16) & 1u);
    return (unsigned short)(u >> 16);
}

// async global->LDS, 16B per lane. lds pointer must be wave-uniform.
static __device__ __forceinline__ void gload_lds16(const void* g, void* lds) {
    unsigned int lo = (unsigned int)(unsigned long long)(uintptr_t)lds;
    __builtin_amdgcn_global_load_lds(
        (const __attribute__((address_space(1))) unsigned int*)(uintptr_t)g,
        (__attribute__((address_space(3))) unsigned int*)lo,
        16, 0, 0);
}

static __device__ __forceinline__ f32x4 mfma16x16x32(short8 a, short8 b, f32x4 c) {
    return __builtin_amdgcn_mfma_f32_16x16x32_bf16(
        __builtin_bit_cast(bf16x8, a), __builtin_bit_cast(bf16x8, b), c, 0, 0, 0);
}

// in [R][C] f32 -> out [C][R] bf16 (transpose + convert). R,C multiples of 64.
__global__ void transpose_cvt_kernel(const float* __restrict__ in,
                                     unsigned short* __restrict__ out,
                                     int R, int C) {
    __shared__ float tile[64][65];
    const int t = (int)threadIdx.x;           // 0..255
    const int r0 = (int)blockIdx.y * 64;
    const int c0 = (int)blockIdx.x * 64;
    #pragma unroll
    for (int q = 0; q < 16; ++q) {
        int lin = q * 256 + t;
        int row = lin >> 6, col = lin & 63;
        tile[row][col] = in[(size_t)(r0 + row) * C + (c0 + col)];
    }
    __syncthreads();
    #pragma unroll
    for (int q = 0; q < 16; ++q) {
        int lin = q * 256 + t;
        int orow = lin >> 6, ocol = lin & 63;
        out[(size_t)(c0 + orow) * R + (r0 + ocol)] = f32_to_bf16_rn(tile[ocol][orow]);
    }
}

// flat f32 -> bf16 convert, 4 elems/thread
__global__ void cvt_kernel(const float* __restrict__ in,
                           unsigned short* __restrict__ out, int n4) {
    int i = (int)(blockIdx.x * blockDim.x + threadIdx.x);
    if (i >= n4) return;
    float4 v = ((const float4*)in)[i];
    ushort4 o = make_ushort4(f32_to_bf16_rn(v.x), f32_to_bf16_rn(v.y),
                             f32_to_bf16_rn(v.z), f32_to_bf16_rn(v.w));
    ((ushort4*)out)[i] = o;
}

// Mcirc[p][n] = bf16(memory[(p+n) & (D-1)]), one block per row p
__global__ void mcirc_kernel(const float* __restrict__ memv,
                             unsigned short* __restrict__ mc) {
    __shared__ unsigned short mb[DD];
    const int t = (int)threadIdx.x;           // 0..255
    for (int q = t; q < DD; q += 256) mb[q] = f32_to_bf16_rn(memv[q]);
    __syncthreads();
    const int p = (int)blockIdx.x;
    unsigned short* row = mc + (size_t)p * DD;
    #pragma unroll
    for (int it = 0; it < 4; ++it) {
        int n = (t + it * 256) * 4;
        ushort4 o = make_ushort4(mb[(p + n) & (DD - 1)],
                                 mb[(p + n + 1) & (DD - 1)],
                                 mb[(p + n + 2) & (DD - 1)],
                                 mb[(p + n + 3) & (DD - 1)]);
        ((ushort4*)row)[n >> 2] = o;
    }
}

// ---------------------------------------------------------------------------
// 256x256-tile 8-phase GEMM (C[m][n] = sum_k A[m,k]*B[n,k], A/B row-major [4096][4096] bf16)
// EPI==0: Cout[m*4096+n] = C ; EPI==1: atomicAdd memv[(m+n)&4095] += C
// LDS layout per op tile (256x64 bf16 = 32KB): 16x32-subtiled, subtile id
// s = (row>>4)*2 + (col>>5), within: r=row&15, c=(col&31) ^ (((row>>3)&1)<<4);
// byte = s*1024 + r*64 + c*2. Staged via pre-swizzled global source (XOR cancels).
// ---------------------------------------------------------------------------
template <int EPI>
__global__ __launch_bounds__(512, 2) void gemm8(
    const unsigned short* __restrict__ A, const unsigned short* __restrict__ B,
    float* __restrict__ Cout, float* __restrict__ memv) {
    __shared__ unsigned short lds[2][2][16384];  // [buf][op A=0/B=1][256*64] = 128 KiB
    const int tid = (int)threadIdx.x;
    const int w = tid >> 6, l = tid & 63;
    const int wr = w >> 2, wc = w & 3;           // 2(M) x 4(N) wave grid
    const int fr = l & 15, fq = l >> 4;

    // bijective XCD swizzle (nwg=256, 256%8==0)
    const int bid = (int)blockIdx.x;
    const int bs = (bid & 7) * 32 + (bid >> 3);
    const int m0 = (bs >> 4) * 256;
    const int n0 = (bs & 15) * 256;

    const unsigned short* GA = A + (size_t)m0 * 4096;
    const unsigned short* GB = B + (size_t)n0 * 4096;

    // staging: per (h,j): subtile s=j*8+w; lane l -> row = h*128 + (s>>1)*16 + (l>>2),
    // col(k) = (s&1)*32 + ((l&3)*8 ^ ((l>>5)<<4))   (pre-swizzled source)
    const unsigned int rr = (unsigned)(l >> 2);
    const unsigned int cc = (unsigned)(((l & 3) * 8) ^ ((l >> 5) << 4));
    const unsigned int eoff0 = (((unsigned)w >> 1) * 16 + rr) * 4096u + ((unsigned)w & 1) * 32 + cc;
    const unsigned int eoff1 = (((unsigned)(8 + w) >> 1) * 16 + rr) * 4096u + ((unsigned)(8 + w) & 1) * 32 + cc;

    // ds_read fragment base offsets (bytes): frag(mi,ks) at +(mi*2+ks)*1024
    const unsigned int c2 = (unsigned)((fq * 16) ^ ((fr >> 3) << 5));
    const unsigned int a_off = (unsigned)(wr * 16384 + fr * 64) + c2;
    const unsigned int b_off = (unsigned)(wc * 8192 + fr * 64) + c2;

    f32x4 acc[8][4];
    #pragma unroll
    for (int i = 0; i < 8; ++i)
        #pragma unroll
        for (int j = 0; j < 4; ++j) acc[i][j] = (f32x4){0.f, 0.f, 0.f, 0.f};

#define SH(GBASE, BUF, OP, T, H) do {                                             \
    gload_lds16((GBASE) + eoff0 + (unsigned)(T) * 64u + (unsigned)(H) * 524288u,  \
                &lds[BUF][OP][(((H) * 16 + 0 + w)) * 512]);                       \
    gload_lds16((GBASE) + eoff1 + (unsigned)(T) * 64u + (unsigned)(H) * 524288u,  \
                &lds[BUF][OP][(((H) * 16 + 8 + w)) * 512]);                       \
} while (0)

#define MFMA_Q(MB, NB, AARR, BARR) do {                                           \
    _Pragma("unroll") for (int _mi = 0; _mi < 4; ++_mi)                           \
    _Pragma("unroll") for (int _ni = 0; _ni < 2; ++_ni)                           \
    _Pragma("unroll") for (int _ks = 0; _ks < 2; ++_ks)                           \
        acc[(MB) + _mi][(NB) + _ni] =                                             \
            mfma16x16x32(AARR[_mi * 2 + _ks], BARR[_ni * 2 + _ks],                \
                         acc[(MB) + _mi][(NB) + _ni]);                            \
} while (0)

#define LGK0() asm volatile("s_waitcnt lgkmcnt(0)" ::: "memory")
#define BARR() __builtin_amdgcn_s_barrier()

    // prologue: t0 {Bh0,Ah0,Ah1,Bh1}, t1 {Bh0,Ah0,Ah1} -> wait t0 landed
    SH(GB, 0, 1, 0, 0);
    SH(GA, 0, 0, 0, 0);
    SH(GA, 0, 0, 0, 1);
    SH(GB, 0, 1, 0, 1);
    SH(GB, 1, 1, 1, 0);
    SH(GA, 1, 0, 1, 0);
    SH(GA, 1, 0, 1, 1);
    asm volatile("s_waitcnt vmcnt(6)" ::: "memory");
    BARR();

    short8 areg[8], b0r[4], b1r[4];
    for (int t = 0; t < NT; ++t) {
        const int cur = t & 1, nxt = cur ^ 1;
        const char* LAc = (const char*)&lds[cur][0][0];
        const char* LBc = (const char*)&lds[cur][1][0];
        // ---- phase 0: read A-mh0 + B-nh0; stage (t+1).Bh1 -> nxt
        #pragma unroll
        for (int i = 0; i < 4; ++i)
            #pragma unroll
            for (int ks = 0; ks < 2; ++ks)
                areg[i * 2 + ks] = *(const short8*)(LAc + a_off + (i * 2 + ks) * 1024);
        #pragma unroll
        for (int i = 0; i < 2; ++i)
            #pragma unroll
            for (int ks = 0; ks < 2; ++ks)
                b0r[i * 2 + ks] = *(const short8*)(LBc + b_off + (i * 2 + ks) * 1024);
        if (t < NT - 1) SH(GB, nxt, 1, t + 1, 1);
        BARR(); LGK0();
        __builtin_amdgcn_s_setprio(1);
        MFMA_Q(0, 0, areg, b0r);
        __builtin_amdgcn_s_setprio(0);
        BARR();
        // ---- phase 1: read B-nh1
        #pragma unroll
        for (int i = 0; i < 2; ++i)
            #pragma unroll
            for (int ks = 0; ks < 2; ++ks)
                b1r[i * 2 + ks] = *(const short8*)(LBc + b_off + 4096 + (i * 2 + ks) * 1024);
        BARR(); LGK0();
        __builtin_amdgcn_s_setprio(1);
        MFMA_Q(0, 2, areg, b1r);
        __builtin_amdgcn_s_setprio(0);
        BARR();
        // ---- phase 2: read A-mh1; stage (t+2).Bh0 -> cur
        #pragma unroll
        for (int i = 0; i < 4; ++i)
            #pragma unroll
            for (int ks = 0; ks < 2; ++ks)
                areg[i * 2 + ks] = *(const short8*)(LAc + a_off + 8192 + (i * 2 + ks) * 1024);
        if (t < NT - 2) SH(GB, cur, 1, t + 2, 0);
        BARR(); LGK0();
        __builtin_amdgcn_s_setprio(1);
        MFMA_Q(4, 2, areg, b1r);
        __builtin_amdgcn_s_setprio(0);
        BARR();
        // ---- phase 3: stage (t+2).Ah0+Ah1 -> cur
        if (t < NT - 2) { SH(GA, cur, 0, t + 2, 0); SH(GA, cur, 0, t + 2, 1); }
        BARR(); LGK0();
        __builtin_amdgcn_s_setprio(1);
        MFMA_Q(4, 0, areg, b0r);
        __builtin_amdgcn_s_setprio(0);
        // ---- K-tile boundary: counted drain (t+1 fully landed, t+2's 3 halves in flight)
        if (t < NT - 2) asm volatile("s_waitcnt vmcnt(6)" ::: "memory");
        else            asm volatile("s_waitcnt vmcnt(0)" ::: "memory");
        BARR();
    }

    if constexpr (EPI == 0) {
        #pragma unroll
        for (int mi = 0; mi < 8; ++mi) {
            const int gr = m0 + wr * 128 + mi * 16 + fq * 4;
            #pragma unroll
            for (int jr = 0; jr < 4; ++jr) {
                float* rowp = Cout + (size_t)(gr + jr) * 4096 + n0 + wc * 64 + fr;
                #pragma unroll
                for (int ni = 0; ni < 4; ++ni) rowp[ni * 16] = acc[mi][ni][jr];
            }
        }
    } else {
        __syncthreads();
        float* bins = (float*)&lds[0][0][0];
        bins[tid] = 0.f;
        __syncthreads();
        #pragma unroll
        for (int mi = 0; mi < 8; ++mi)
            #pragma unroll
            for (int ni = 0; ni < 4; ++ni)
                #pragma unroll
                for (int jr = 0; jr < 4; ++jr) {
                    int ml = wr * 128 + mi * 16 + fq * 4 + jr;
                    int nl = wc * 64 + ni * 16 + fr;
                    atomicAdd(&bins[ml + nl], acc[mi][ni][jr]);
                }
        __syncthreads();
        atomicAdd(&memv[(m0 + n0 + tid) & (DD - 1)], bins[tid]);
    }
#undef SH
#undef MFMA_Q
#undef LGK0
#undef BARR
}

extern "C" void kernel_launch(void* const* d_in, const int* in_sizes, int n_in,
                              void* d_out, int out_size, void* d_ws, size_t ws_size,
                              hipStream_t stream) {
    const float* keys    = (const float*)d_in[0];
    const float* values  = (const float*)d_in[1];
    const float* queries = (const float*)d_in[2];
    float* out = (float*)d_out;
    char* ws = (char*)d_ws;

    unsigned short* A1 = (unsigned short*)ws;                          // 32MB: keys^T bf16, later queries bf16
    unsigned short* Bt = (unsigned short*)(ws + (size_t)(32 << 20));   // 32MB: values^T bf16, later Mcirc
    float* memv = (float*)(ws + (size_t)(64 << 20));                   // 16KB: memory vector

    hipMemsetAsync(memv, 0, DD * sizeof(float), stream);

    dim3 tgrid(DD / 64, NPAIR / 64);
    transpose_cvt_kernel<<<tgrid, 256, 0, stream>>>(keys, A1, NPAIR, DD);
    transpose_cvt_kernel<<<tgrid, 256, 0, stream>>>(values, Bt, NPAIR, DD);

    gemm8<1><<<256, 512, 0, stream>>>(A1, Bt, nullptr, memv);

    mcirc_kernel<<<DD, 256, 0, stream>>>(memv, Bt);

    cvt_kernel<<<(NQUERY * DD / 4) / 256, 256, 0, stream>>>(queries, A1, NQUERY * DD / 4);

    gemm8<0><<<256, 512, 0, stream>>>(A1, Bt, out, nullptr);
}

// Round 3
// 367.350 us; speedup vs baseline: 1.2151x; 1.0224x over previous
//
#include <hip/hip_runtime.h>
#include <hip/hip_bf16.h>
#include <stdint.h>

#define DD 4096
#define NPAIR 4096
#define NQUERY 4096
#define NT 64   // K / 64

typedef __attribute__((ext_vector_type(4))) float f32x4;
typedef __attribute__((ext_vector_type(8))) short short8;
typedef __attribute__((ext_vector_type(8))) __bf16 bf16x8;

static __device__ __forceinline__ unsigned short f32_to_bf16_rn(float f) {
    unsigned int u = __float_as_uint(f);
    u += 0x7fffu + ((u >> 16) & 1u);
    return (unsigned short)(u >> 16);
}

// async global->LDS, 16B per lane. lds pointer must be wave-uniform.
static __device__ __forceinline__ void gload_lds16(const void* g, void* lds) {
    unsigned int lo = (unsigned int)(unsigned long long)(uintptr_t)lds;
    __builtin_amdgcn_global_load_lds(
        (const __attribute__((address_space(1))) unsigned int*)(uintptr_t)g,
        (__attribute__((address_space(3))) unsigned int*)lo,
        16, 0, 0);
}

static __device__ __forceinline__ f32x4 mfma16x16x32(short8 a, short8 b, f32x4 c) {
    return __builtin_amdgcn_mfma_f32_16x16x32_bf16(
        __builtin_bit_cast(bf16x8, a), __builtin_bit_cast(bf16x8, b), c, 0, 0, 0);
}

// in [R][C] f32 -> out [C][R] bf16 (transpose + convert). R,C multiples of 64.
__global__ void transpose_cvt_kernel(const float* __restrict__ in,
                                     unsigned short* __restrict__ out,
                                     int R, int C) {
    __shared__ float tile[64][65];
    const int t = (int)threadIdx.x;           // 0..255
    const int r0 = (int)blockIdx.y * 64;
    const int c0 = (int)blockIdx.x * 64;
    #pragma unroll
    for (int q = 0; q < 16; ++q) {
        int lin = q * 256 + t;
        int row = lin >> 6, col = lin & 63;
        tile[row][col] = in[(size_t)(r0 + row) * C + (c0 + col)];
    }
    __syncthreads();
    #pragma unroll
    for (int q = 0; q < 16; ++q) {
        int lin = q * 256 + t;
        int orow = lin >> 6, ocol = lin & 63;
        out[(size_t)(c0 + orow) * R + (r0 + ocol)] = f32_to_bf16_rn(tile[ocol][orow]);
    }
}

// flat f32 -> bf16 convert, 4 elems/thread
__global__ void cvt_kernel(const float* __restrict__ in,
                           unsigned short* __restrict__ out, int n4) {
    int i = (int)(blockIdx.x * blockDim.x + threadIdx.x);
    if (i >= n4) return;
    float4 v = ((const float4*)in)[i];
    ushort4 o = make_ushort4(f32_to_bf16_rn(v.x), f32_to_bf16_rn(v.y),
                             f32_to_bf16_rn(v.z), f32_to_bf16_rn(v.w));
    ((ushort4*)out)[i] = o;
}

// Mcirc[p][n] = bf16(memory[(p+n) & (D-1)]), one block per row p
__global__ void mcirc_kernel(const float* __restrict__ memv,
                             unsigned short* __restrict__ mc) {
    __shared__ unsigned short mb[DD];
    const int t = (int)threadIdx.x;           // 0..255
    for (int q = t; q < DD; q += 256) mb[q] = f32_to_bf16_rn(memv[q]);
    __syncthreads();
    const int p = (int)blockIdx.x;
    unsigned short* row = mc + (size_t)p * DD;
    #pragma unroll
    for (int it = 0; it < 4; ++it) {
        int n = (t + it * 256) * 4;
        ushort4 o = make_ushort4(mb[(p + n) & (DD - 1)],
                                 mb[(p + n + 1) & (DD - 1)],
                                 mb[(p + n + 2) & (DD - 1)],
                                 mb[(p + n + 3) & (DD - 1)]);
        ((ushort4*)row)[n >> 2] = o;
    }
}

// ---------------------------------------------------------------------------
// 256x256-tile 8-phase GEMM (C[m][n] = sum_k A[m,k]*B[n,k], A/B row-major [4096][4096] bf16)
// EPI==0: Cout[m*4096+n] = C ; EPI==1: atomicAdd memv[(m+n)&4095] += C
// LDS layout per op tile (256x64 bf16 = 32KB): 16x32-subtiled, subtile id
// s = (row>>4)*2 + (col>>5), within: r=row&15, c=(col&31) ^ (((row>>3)&1)<<4);
// byte = s*1024 + r*64 + c*2. Staged via pre-swizzled global source (XOR cancels).
// Fragment ds_reads are inline asm so SIInsertWaitcnts cannot inject vmcnt(0)
// drains (LDS-DMA alias conservatism); ordering is by explicit lgkmcnt(0) +
// sched_barrier(0) (rule #18) and the counted vmcnt(6) at the K-tile boundary.
// ---------------------------------------------------------------------------
#define DSR(dst, addr, off) \
    asm volatile("ds_read_b128 %0, %1 offset:" #off : "=v"(dst) : "v"(addr))

template <int EPI>
__global__ __launch_bounds__(512, 2) void gemm8(
    const unsigned short* __restrict__ A, const unsigned short* __restrict__ B,
    float* __restrict__ Cout, float* __restrict__ memv) {
    __shared__ unsigned short lds[2][2][16384];  // [buf][op A=0/B=1][256*64] = 128 KiB
    const int tid = (int)threadIdx.x;
    const int w = tid >> 6, l = tid & 63;
    const int wr = w >> 2, wc = w & 3;           // 2(M) x 4(N) wave grid
    const int fr = l & 15, fq = l >> 4;

    // bijective XCD swizzle (nwg=256, 256%8==0)
    const int bid = (int)blockIdx.x;
    const int bs = (bid & 7) * 32 + (bid >> 3);
    const int m0 = (bs >> 4) * 256;
    const int n0 = (bs & 15) * 256;

    const unsigned short* GA = A + (size_t)m0 * 4096;
    const unsigned short* GB = B + (size_t)n0 * 4096;

    // staging: per (h,j): subtile s=j*8+w; lane l -> row = h*128 + (s>>1)*16 + (l>>2),
    // col(k) = (s&1)*32 + ((l&3)*8 ^ ((l>>5)<<4))   (pre-swizzled source)
    const unsigned int rr = (unsigned)(l >> 2);
    const unsigned int cc = (unsigned)(((l & 3) * 8) ^ ((l >> 5) << 4));
    const unsigned int eoff0 = (((unsigned)w >> 1) * 16 + rr) * 4096u + ((unsigned)w & 1) * 32 + cc;
    const unsigned int eoff1 = (((unsigned)(8 + w) >> 1) * 16 + rr) * 4096u + ((unsigned)(8 + w) & 1) * 32 + cc;

    // ds_read fragment base addresses (bytes); frag(mi,ks) at +(mi*2+ks)*1024
    const unsigned int c2 = (unsigned)((fq * 16) ^ ((fr >> 3) << 5));
    const unsigned int ldsbase = (unsigned int)(uintptr_t)&lds[0][0][0];
    const unsigned int aA0 = ldsbase + (unsigned)(wr * 16384 + fr * 64) + c2;
    const unsigned int aB0 = ldsbase + 32768u + (unsigned)(wc * 8192 + fr * 64) + c2;
    const unsigned int aA1 = aA0 + 65536u;
    const unsigned int aB1 = aB0 + 65536u;

    f32x4 acc[8][4];
    #pragma unroll
    for (int i = 0; i < 8; ++i)
        #pragma unroll
        for (int j = 0; j < 4; ++j) acc[i][j] = (f32x4){0.f, 0.f, 0.f, 0.f};

#define SH(GBASE, BUF, OP, T, H) do {                                             \
    gload_lds16((GBASE) + eoff0 + (unsigned)(T) * 64u + (unsigned)(H) * 524288u,  \
                &lds[BUF][OP][(((H) * 16 + 0 + w)) * 512]);                       \
    gload_lds16((GBASE) + eoff1 + (unsigned)(T) * 64u + (unsigned)(H) * 524288u,  \
                &lds[BUF][OP][(((H) * 16 + 8 + w)) * 512]);                       \
} while (0)

#define MFMA_Q(MB, NB, AARR, BARRr) do {                                          \
    _Pragma("unroll") for (int _mi = 0; _mi < 4; ++_mi)                           \
    _Pragma("unroll") for (int _ni = 0; _ni < 2; ++_ni)                           \
    _Pragma("unroll") for (int _ks = 0; _ks < 2; ++_ks)                           \
        acc[(MB) + _mi][(NB) + _ni] =                                             \
            mfma16x16x32(AARR[_mi * 2 + _ks], BARRr[_ni * 2 + _ks],               \
                         acc[(MB) + _mi][(NB) + _ni]);                            \
} while (0)

#define LGK0() asm volatile("s_waitcnt lgkmcnt(0)" ::: "memory")
#define VMC6() asm volatile("s_waitcnt vmcnt(6)" ::: "memory")
#define VMC0() asm volatile("s_waitcnt vmcnt(0)" ::: "memory")
#define SCB0() __builtin_amdgcn_sched_barrier(0)
#define BARR() __builtin_amdgcn_s_barrier()

#define RD_A(aaddr, base_off) do {                                                \
    DSR(areg[0], aaddr, base_off + 0);    DSR(areg[1], aaddr, base_off + 1024);   \
    DSR(areg[2], aaddr, base_off + 2048); DSR(areg[3], aaddr, base_off + 3072);   \
    DSR(areg[4], aaddr, base_off + 4096); DSR(areg[5], aaddr, base_off + 5120);   \
    DSR(areg[6], aaddr, base_off + 6144); DSR(areg[7], aaddr, base_off + 7168);   \
} while (0)

    // prologue: t0 {Bh0,Ah0,Ah1,Bh1}, t1 {Bh0,Ah0,Ah1} -> wait t0 landed
    SH(GB, 0, 1, 0, 0);
    SH(GA, 0, 0, 0, 0);
    SH(GA, 0, 0, 0, 1);
    SH(GB, 0, 1, 0, 1);
    SH(GB, 1, 1, 1, 0);
    SH(GA, 1, 0, 1, 0);
    SH(GA, 1, 0, 1, 1);
    VMC6();
    BARR();

    short8 areg[8], b0r[4], b1r[4];

#define KSTEP(t, CUR, NXT, aA, aB) do {                                           \
    /* phase 0: read A-mh0 + B-nh0; stage (t+1).Bh1 -> NXT */                     \
    RD_A(aA, 0);                                                                  \
    DSR(b0r[0], aB, 0);    DSR(b0r[1], aB, 1024);                                 \
    DSR(b0r[2], aB, 2048); DSR(b0r[3], aB, 3072);                                 \
    if ((t) < NT - 1) SH(GB, NXT, 1, (t) + 1, 1);                                 \
    BARR(); LGK0(); SCB0();                                                       \
    __builtin_amdgcn_s_setprio(1);                                                \
    MFMA_Q(0, 0, areg, b0r);                                                      \
    __builtin_amdgcn_s_setprio(0);                                                \
    BARR();                                                                       \
    /* phase 1: read B-nh1 */                                                     \
    DSR(b1r[0], aB, 4096); DSR(b1r[1], aB, 5120);                                 \
    DSR(b1r[2], aB, 6144); DSR(b1r[3], aB, 7168);                                 \
    BARR(); LGK0(); SCB0();                                                       \
    __builtin_amdgcn_s_setprio(1);                                                \
    MFMA_Q(0, 2, areg, b1r);                                                      \
    __builtin_amdgcn_s_setprio(0);                                                \
    BARR();                                                                       \
    /* phase 2: read A-mh1; stage (t+2).Bh0 -> CUR */                             \
    RD_A(aA, 8192);                                                               \
    if ((t) < NT - 2) SH(GB, CUR, 1, (t) + 2, 0);                                 \
    BARR(); LGK0(); SCB0();                                                       \
    __builtin_amdgcn_s_setprio(1);                                                \
    MFMA_Q(4, 2, areg, b1r);                                                      \
    __builtin_amdgcn_s_setprio(0);                                                \
    BARR();                                                                       \
    /* phase 3: stage (t+2).Ah0+Ah1 -> CUR */                                     \
    if ((t) < NT - 2) { SH(GA, CUR, 0, (t) + 2, 0); SH(GA, CUR, 0, (t) + 2, 1); } \
    __builtin_amdgcn_s_setprio(1);                                                \
    MFMA_Q(4, 0, areg, b0r);                                                      \
    __builtin_amdgcn_s_setprio(0);                                                \
    /* K-tile boundary: counted drain (t+1 landed, t+2's 3 halves in flight) */   \
    if ((t) < NT - 2) VMC6(); else VMC0();                                        \
    BARR();                                                                       \
} while (0)

    for (int u = 0; u < NT / 2; ++u) {
        const int t0 = 2 * u;
        KSTEP(t0, 0, 1, aA0, aB0);
        KSTEP(t0 + 1, 1, 0, aA1, aB1);
    }

    if constexpr (EPI == 0) {
        #pragma unroll
        for (int mi = 0; mi < 8; ++mi) {
            const int gr = m0 + wr * 128 + mi * 16 + fq * 4;
            #pragma unroll
            for (int jr = 0; jr < 4; ++jr) {
                float* rowp = Cout + (size_t)(gr + jr) * 4096 + n0 + wc * 64 + fr;
                #pragma unroll
                for (int ni = 0; ni < 4; ++ni) rowp[ni * 16] = acc[mi][ni][jr];
            }
        }
    } else {
        __syncthreads();
        float* bins = (float*)&lds[0][0][0];
        bins[tid] = 0.f;
        __syncthreads();
        #pragma unroll
        for (int mi = 0; mi < 8; ++mi)
            #pragma unroll
            for (int ni = 0; ni < 4; ++ni)
                #pragma unroll
                for (int jr = 0; jr < 4; ++jr) {
                    int ml = wr * 128 + mi * 16 + fq * 4 + jr;
                    int nl = wc * 64 + ni * 16 + fr;
                    atomicAdd(&bins[ml + nl], acc[mi][ni][jr]);
                }
        __syncthreads();
        atomicAdd(&memv[(m0 + n0 + tid) & (DD - 1)], bins[tid]);
    }
#undef KSTEP
#undef RD_A
#undef SH
#undef MFMA_Q
#undef LGK0
#undef VMC6
#undef VMC0
#undef SCB0
#undef BARR
}

extern "C" void kernel_launch(void* const* d_in, const int* in_sizes, int n_in,
                              void* d_out, int out_size, void* d_ws, size_t ws_size,
                              hipStream_t stream) {
    const float* keys    = (const float*)d_in[0];
    const float* values  = (const float*)d_in[1];
    const float* queries = (const float*)d_in[2];
    float* out = (float*)d_out;
    char* ws = (char*)d_ws;

    unsigned short* A1 = (unsigned short*)ws;                          // 32MB: keys^T bf16, later queries bf16
    unsigned short* Bt = (unsigned short*)(ws + (size_t)(32 << 20));   // 32MB: values^T bf16, later Mcirc
    float* memv = (float*)(ws + (size_t)(64 << 20));                   // 16KB: memory vector

    hipMemsetAsync(memv, 0, DD * sizeof(float), stream);

    dim3 tgrid(DD / 64, NPAIR / 64);
    transpose_cvt_kernel<<<tgrid, 256, 0, stream>>>(keys, A1, NPAIR, DD);
    transpose_cvt_kernel<<<tgrid, 256, 0, stream>>>(values, Bt, NPAIR, DD);

    gemm8<1><<<256, 512, 0, stream>>>(A1, Bt, nullptr, memv);

    mcirc_kernel<<<DD, 256, 0, stream>>>(memv, Bt);

    cvt_kernel<<<(NQUERY * DD / 4) / 256, 256, 0, stream>>>(queries, A1, NQUERY * DD / 4);

    gemm8<0><<<256, 512, 0, stream>>>(A1, Bt, out, nullptr);
}

// Round 4
// 187.624 us; speedup vs baseline: 2.3790x; 1.9579x over previous
//
#include <hip/hip_runtime.h>
#include <hip/hip_bf16.h>
#include <stdint.h>

#define DD 4096
#define NPAIR 4096
#define NQUERY 4096
#define PAIRS_PER_BLOCK 8

// padded LDS slot: breaks power-of-2 stride bank conflicts (<=2-way mostly)
#define SLOT(i) ((i) + ((i) >> 5))

// base-4 digit reversal of a 12-bit index
static __device__ __forceinline__ int drev(int j) {
    unsigned r = __brev((unsigned)j) >> 20;          // bit-reverse 12 bits
    return (int)(((r & 0x555u) << 1) | ((r >> 1) & 0x555u));  // fix digit-internal order
}

// In-place radix-4 DIT FFT, N=4096. Input digit-reversed, output natural order.
// twr/twi hold w_4096^j = exp(-2*pi*i*j/4096) for j in [0,1024). INV conjugates.
// Caller must __syncthreads() between the LDS fill and this call.
template <int INV>
static __device__ void fft4096(float* xr, float* xi,
                               const float* twr, const float* twi, int tid) {
    #pragma unroll
    for (int st = 0; st < 6; ++st) {
        const int s = 1 << (2 * st);
        const int step = 1024 >> (2 * st);
        #pragma unroll
        for (int q = 0; q < 4; ++q) {
            const int b = tid + 256 * q;
            const int k = b & (s - 1);
            const int g = b >> (2 * st);
            const int i0 = (g << (2 * st + 2)) + k;
            const int i1 = i0 + s, i2 = i0 + 2 * s, i3 = i0 + 3 * s;
            const int tj = k * step;                 // < 1024
            const float w1r = twr[tj];
            const float w1i = INV ? -twi[tj] : twi[tj];
            const float w2r = w1r * w1r - w1i * w1i, w2i = 2.f * w1r * w1i;
            const float w3r = w2r * w1r - w2i * w1i, w3i = w2r * w1i + w2i * w1r;
            const float a0r = xr[SLOT(i0)], a0i = xi[SLOT(i0)];
            const float x1r = xr[SLOT(i1)], x1i = xi[SLOT(i1)];
            const float x2r = xr[SLOT(i2)], x2i = xi[SLOT(i2)];
            const float x3r = xr[SLOT(i3)], x3i = xi[SLOT(i3)];
            const float t1r = x1r * w1r - x1i * w1i, t1i = x1r * w1i + x1i * w1r;
            const float t2r = x2r * w2r - x2i * w2i, t2i = x2r * w2i + x2i * w2r;
            const float t3r = x3r * w3r - x3i * w3i, t3i = x3r * w3i + x3i * w3r;
            const float s02r = a0r + t2r, s02i = a0i + t2i;
            const float d02r = a0r - t2r, d02i = a0i - t2i;
            const float s13r = t1r + t3r, s13i = t1i + t3i;
            const float d13r = t1r - t3r, d13i = t1i - t3i;
            xr[SLOT(i0)] = s02r + s13r;  xi[SLOT(i0)] = s02i + s13i;
            xr[SLOT(i2)] = s02r - s13r;  xi[SLOT(i2)] = s02i - s13i;
            if (!INV) {  // y1 = d02 - i*d13 ; y3 = d02 + i*d13
                xr[SLOT(i1)] = d02r + d13i;  xi[SLOT(i1)] = d02i - d13r;
                xr[SLOT(i3)] = d02r - d13i;  xi[SLOT(i3)] = d02i + d13r;
            } else {     // conjugated cross terms
                xr[SLOT(i1)] = d02r - d13i;  xi[SLOT(i1)] = d02i + d13r;
                xr[SLOT(i3)] = d02r + d13i;  xi[SLOT(i3)] = d02i - d13r;
            }
        }
        __syncthreads();
    }
}

static __device__ __forceinline__ void init_twiddle(float* twr, float* twi, int tid) {
    for (int j = tid; j < 1024; j += 256) {
        const float ang = -6.2831853071795864769f * (float)j / 4096.f;
        twr[j] = cosf(ang);
        twi[j] = sinf(ang);
    }
}

// store: for each pair i, Z = FFT(k_i + i*v_i); P[f] = (Z[f]^2 - conj(Z[-f])^2)/(4i)
// = FFT(k)*FFT(v); accumulate Mfreq += P.
__global__ __launch_bounds__(256) void store_kernel(
    const float* __restrict__ keys, const float* __restrict__ values,
    float* __restrict__ Mre, float* __restrict__ Mim) {
    __shared__ float xr[4224], xi[4224], twr[1024], twi[1024];
    const int tid = (int)threadIdx.x;
    init_twiddle(twr, twi, tid);

    float mr[16], mi[16];
    #pragma unroll
    for (int r = 0; r < 16; ++r) { mr[r] = 0.f; mi[r] = 0.f; }

    for (int p = 0; p < PAIRS_PER_BLOCK; ++p) {
        const int pair = (int)blockIdx.x * PAIRS_PER_BLOCK + p;
        const float* krow = keys + (size_t)pair * DD;
        const float* vrow = values + (size_t)pair * DD;
        __syncthreads();  // previous iteration's reads done; twiddles visible
        #pragma unroll
        for (int q = 0; q < 4; ++q) {
            const float4 kv = ((const float4*)krow)[tid + 256 * q];
            const float4 vv = ((const float4*)vrow)[tid + 256 * q];
            const int j = (tid + 256 * q) * 4;
            int d0 = SLOT(drev(j + 0)), d1 = SLOT(drev(j + 1));
            int d2 = SLOT(drev(j + 2)), d3 = SLOT(drev(j + 3));
            xr[d0] = kv.x; xi[d0] = vv.x;
            xr[d1] = kv.y; xi[d1] = vv.y;
            xr[d2] = kv.z; xi[d2] = vv.z;
            xr[d3] = kv.w; xi[d3] = vv.w;
        }
        __syncthreads();
        fft4096<0>(xr, xi, twr, twi, tid);
        #pragma unroll
        for (int r = 0; r < 16; ++r) {
            const int f = tid + 256 * r;
            const int fn = (DD - f) & (DD - 1);
            const float ar = xr[SLOT(f)],  ai = xi[SLOT(f)];
            const float br = xr[SLOT(fn)], bi = xi[SLOT(fn)];
            // S = a^2 - conj(b)^2 ; P = S/(4i) = (S.im/4, -S.re/4)
            const float a2r = ar * ar - ai * ai, a2i = 2.f * ar * ai;
            const float c2r = br * br - bi * bi, c2i = -2.f * br * bi;
            const float Sr = a2r - c2r, Si = a2i - c2i;
            mr[r] += 0.25f * Si;
            mi[r] -= 0.25f * Sr;
        }
    }
    #pragma unroll
    for (int r = 0; r < 16; ++r) {
        const int f = tid + 256 * r;
        atomicAdd(&Mre[f], mr[r]);
        atomicAdd(&Mim[f], mi[r]);
    }
}

// retrieve: 2 queries per block. Z = FFT(q0 + i*q1); W[f] = FM[f]*Z[(-f) mod N];
// IFFT(W) = out_row0 + i*out_row1.
__global__ __launch_bounds__(256) void retrieve_kernel(
    const float* __restrict__ queries, const float* __restrict__ Mre,
    const float* __restrict__ Mim, float* __restrict__ out) {
    __shared__ float xr[4224], xi[4224], twr[1024], twi[1024];
    const int tid = (int)threadIdx.x;
    init_twiddle(twr, twi, tid);

    const int q0 = (int)blockIdx.x * 2, q1 = q0 + 1;
    const float* qrow0 = queries + (size_t)q0 * DD;
    const float* qrow1 = queries + (size_t)q1 * DD;
    #pragma unroll
    for (int q = 0; q < 4; ++q) {
        const float4 a = ((const float4*)qrow0)[tid + 256 * q];
        const float4 b = ((const float4*)qrow1)[tid + 256 * q];
        const int j = (tid + 256 * q) * 4;
        int d0 = SLOT(drev(j + 0)), d1 = SLOT(drev(j + 1));
        int d2 = SLOT(drev(j + 2)), d3 = SLOT(drev(j + 3));
        xr[d0] = a.x; xi[d0] = b.x;
        xr[d1] = a.y; xi[d1] = b.y;
        xr[d2] = a.z; xi[d2] = b.z;
        xr[d3] = a.w; xi[d3] = b.w;
    }
    __syncthreads();
    fft4096<0>(xr, xi, twr, twi, tid);

    // W build in registers: thread owns f = tid + 256r (r<8) and its mirror
    float Wr[16], Wi[16];
    #pragma unroll
    for (int r = 0; r < 8; ++r) {
        const int f = tid + 256 * r;
        if (f == 0) {
            const float z0r = xr[SLOT(0)], z0i = xi[SLOT(0)];
            Wr[0] = Mre[0] * z0r - Mim[0] * z0i;
            Wi[0] = Mre[0] * z0i + Mim[0] * z0r;
            const float zhr = xr[SLOT(2048)], zhi = xi[SLOT(2048)];
            Wr[8] = Mre[2048] * zhr - Mim[2048] * zhi;
            Wi[8] = Mre[2048] * zhi + Mim[2048] * zhr;
        } else {
            const int fn = DD - f;
            const float zfr = xr[SLOT(f)],  zfi = xi[SLOT(f)];
            const float znr = xr[SLOT(fn)], zni = xi[SLOT(fn)];
            const float fmr = Mre[f],  fmi = Mim[f];
            const float gmr = Mre[fn], gmi = Mim[fn];
            Wr[r] = fmr * znr - fmi * zni;       // W[f]  = FM[f]  * Z[-f]
            Wi[r] = fmr * zni + fmi * znr;
            Wr[8 + r] = gmr * zfr - gmi * zfi;   // W[fn] = FM[fn] * Z[f]
            Wi[8 + r] = gmr * zfi + gmi * zfr;
        }
    }
    __syncthreads();
    #pragma unroll
    for (int r = 0; r < 8; ++r) {
        const int f = tid + 256 * r;
        if (f == 0) {
            int d0 = SLOT(drev(0)), dh = SLOT(drev(2048));
            xr[d0] = Wr[0]; xi[d0] = Wi[0];
            xr[dh] = Wr[8]; xi[dh] = Wi[8];
        } else {
            const int fn = DD - f;
            int df = SLOT(drev(f)), dn = SLOT(drev(fn));
            xr[df] = Wr[r];     xi[df] = Wi[r];
            xr[dn] = Wr[8 + r]; xi[dn] = Wi[8 + r];
        }
    }
    __syncthreads();
    fft4096<1>(xr, xi, twr, twi, tid);

    const float sc = 1.f / 4096.f;
    float* orow0 = out + (size_t)q0 * DD;
    float* orow1 = out + (size_t)q1 * DD;
    #pragma unroll
    for (int q = 0; q < 4; ++q) {
        const int j = (tid + 256 * q) * 4;
        float4 o0, o1;
        o0.x = xr[SLOT(j + 0)] * sc; o1.x = xi[SLOT(j + 0)] * sc;
        o0.y = xr[SLOT(j + 1)] * sc; o1.y = xi[SLOT(j + 1)] * sc;
        o0.z = xr[SLOT(j + 2)] * sc; o1.z = xi[SLOT(j + 2)] * sc;
        o0.w = xr[SLOT(j + 3)] * sc; o1.w = xi[SLOT(j + 3)] * sc;
        ((float4*)orow0)[tid + 256 * q] = o0;
        ((float4*)orow1)[tid + 256 * q] = o1;
    }
}

extern "C" void kernel_launch(void* const* d_in, const int* in_sizes, int n_in,
                              void* d_out, int out_size, void* d_ws, size_t ws_size,
                              hipStream_t stream) {
    const float* keys    = (const float*)d_in[0];
    const float* values  = (const float*)d_in[1];
    const float* queries = (const float*)d_in[2];
    float* out = (float*)d_out;
    char* ws = (char*)d_ws;

    float* Mre = (float*)ws;                       // 16KB
    float* Mim = (float*)(ws + 16384);             // 16KB

    hipMemsetAsync(Mre, 0, 2 * DD * sizeof(float), stream);

    store_kernel<<<NPAIR / PAIRS_PER_BLOCK, 256, 0, stream>>>(keys, values, Mre, Mim);
    retrieve_kernel<<<NQUERY / 2, 256, 0, stream>>>(queries, Mre, Mim, out);
}

// Round 5
// 153.850 us; speedup vs baseline: 2.9013x; 1.2195x over previous
//
#include <hip/hip_runtime.h>
#include <stdint.h>

#define DD 4096
#define NPAIR 4096
#define NQUERY 4096
#define PPB 8

// padded LDS slot: +2 floats per 32-float block; keeps float2 alignment,
// <=2-way conflicts on all pass access patterns (analyzed per pass).
#define SLOT2(i) ((i) + ((((i) >> 5)) << 1))

static __device__ __forceinline__ void init_twiddle(float* twr, float* twi, int tid) {
    for (int j = tid; j < 1024; j += 256) {
        const float ang = -6.2831853071795864769f * (float)j / 4096.f;
        twr[j] = cosf(ang);
        twi[j] = sinf(ang);
    }
}

// multiply (ar,ai) by w4096^j (forward table; INV conjugates), j in [0,4096)
template <int INV>
static __device__ __forceinline__ void cmul_tw(const float* twr, const float* twi,
                                               int j, float& ar, float& ai) {
    const int q = j >> 10, r = j & 1023;
    const float cr = twr[r], ci = twi[r];
    // w^j = w^r * (-i)^q : q0:(cr,ci) q1:(ci,-cr) q2:(-cr,-ci) q3:(-ci,cr)
    const float sr = (q & 1) ? ci : cr;
    const float si = (q & 1) ? cr : ci;
    float wr = (q >= 2) ? -sr : sr;
    float wi = ((q == 1) || (q == 2)) ? -si : si;
    if (INV) wi = -wi;
    const float xr = ar, xi = ai;
    ar = xr * wr - xi * wi;
    ai = xr * wi + xi * wr;
}

// in-register 16-point DFT: z[n] -> z[k], natural order both sides.
// Internally n = 4*n1 + n2, k = k1 + 4*k2 (four-step, A=B=4).
template <int INV>
static __device__ __forceinline__ void fft16(float* zr, float* zi) {
    const float K1 = 0.92387953251128674f;   // cos(pi/8)
    const float S1 = 0.38268343236508978f;   // sin(pi/8)
    const float C2 = 0.70710678118654752f;
    float gr[16], gi[16];                    // g[k1*4 + n2]
    #pragma unroll
    for (int n2 = 0; n2 < 4; ++n2) {
        const float x0r = zr[n2],      x0i = zi[n2];
        const float x1r = zr[4 + n2],  x1i = zi[4 + n2];
        const float x2r = zr[8 + n2],  x2i = zi[8 + n2];
        const float x3r = zr[12 + n2], x3i = zi[12 + n2];
        const float s02r = x0r + x2r, s02i = x0i + x2i;
        const float d02r = x0r - x2r, d02i = x0i - x2i;
        const float s13r = x1r + x3r, s13i = x1i + x3i;
        const float d13r = x1r - x3r, d13i = x1i - x3i;
        gr[0 * 4 + n2] = s02r + s13r; gi[0 * 4 + n2] = s02i + s13i;
        gr[2 * 4 + n2] = s02r - s13r; gi[2 * 4 + n2] = s02i - s13i;
        if (!INV) {
            gr[1 * 4 + n2] = d02r + d13i; gi[1 * 4 + n2] = d02i - d13r;
            gr[3 * 4 + n2] = d02r - d13i; gi[3 * 4 + n2] = d02i + d13r;
        } else {
            gr[1 * 4 + n2] = d02r - d13i; gi[1 * 4 + n2] = d02i + d13r;
            gr[3 * 4 + n2] = d02r + d13i; gi[3 * 4 + n2] = d02i - d13r;
        }
    }
    // twiddle w16^{n2*k1} (forward values; INV conjugates)
#define TW16(K, N, WR, WI) do {                                              \
        const float wr_ = (WR), wi_ = INV ? -(WI) : (WI);                    \
        const float xr_ = gr[(K) * 4 + (N)], xi_ = gi[(K) * 4 + (N)];        \
        gr[(K) * 4 + (N)] = xr_ * wr_ - xi_ * wi_;                           \
        gi[(K) * 4 + (N)] = xr_ * wi_ + xi_ * wr_; } while (0)
    TW16(1, 1, K1, -S1);  TW16(1, 2, C2, -C2);   TW16(1, 3, S1, -K1);
    TW16(2, 1, C2, -C2);  TW16(2, 2, 0.f, -1.f); TW16(2, 3, -C2, -C2);
    TW16(3, 1, S1, -K1);  TW16(3, 2, -C2, -C2);  TW16(3, 3, -K1, S1);
#undef TW16
    #pragma unroll
    for (int k1 = 0; k1 < 4; ++k1) {
        const float x0r = gr[k1 * 4 + 0], x0i = gi[k1 * 4 + 0];
        const float x1r = gr[k1 * 4 + 1], x1i = gi[k1 * 4 + 1];
        const float x2r = gr[k1 * 4 + 2], x2i = gi[k1 * 4 + 2];
        const float x3r = gr[k1 * 4 + 3], x3i = gi[k1 * 4 + 3];
        const float s02r = x0r + x2r, s02i = x0i + x2i;
        const float d02r = x0r - x2r, d02i = x0i - x2i;
        const float s13r = x1r + x3r, s13i = x1i + x3i;
        const float d13r = x1r - x3r, d13i = x1i - x3i;
        zr[k1]      = s02r + s13r; zi[k1]      = s02i + s13i;
        zr[k1 + 8]  = s02r - s13r; zi[k1 + 8]  = s02i - s13i;
        if (!INV) {
            zr[k1 + 4]  = d02r + d13i; zi[k1 + 4]  = d02i - d13r;
            zr[k1 + 12] = d02r - d13i; zi[k1 + 12] = d02i + d13r;
        } else {
            zr[k1 + 4]  = d02r - d13i; zi[k1 + 4]  = d02i + d13r;
            zr[k1 + 12] = d02r + d13i; zi[k1 + 12] = d02i - d13r;
        }
    }
}

// 4096-pt FFT, natural-order in/out in padded LDS arrays xr/xi.
// Four-step: 4096 = 16 x (16 x 16); 3 register-FFT16 passes, 2 LDS transposes.
// Caller must __syncthreads() between filling xr/xi and calling this.
// Ends with __syncthreads() (result visible to all threads).
template <int INV>
static __device__ void fft4096r(float* xr, float* xi,
                                const float* twr, const float* twi, int tid) {
    float zr[16], zi[16];
    // ---- pass 1: thread t = n2 in [0,256); FFT16 over n1 (stride 256)
    #pragma unroll
    for (int n = 0; n < 16; ++n) {
        const int a = SLOT2(n * 256 + tid);
        zr[n] = xr[a]; zi[n] = xi[a];
    }
    fft16<INV>(zr, zi);
    #pragma unroll
    for (int k = 1; k < 16; ++k)
        cmul_tw<INV>(twr, twi, tid * k, zr[k], zi[k]);
    // same address set per thread -> no sync between read and write
    #pragma unroll
    for (int k = 0; k < 16; ++k) {
        const int a = SLOT2(k * 256 + tid);
        xr[a] = zr[k]; xi[a] = zi[k];
    }
    __syncthreads();
    // ---- pass 2: k1 = t>>4, m2 = t&15; FFT16 over m1 (stride 16)
    const int base2 = (tid >> 4) * 256 + (tid & 15);
    #pragma unroll
    for (int m = 0; m < 16; ++m) {
        const int a = SLOT2(base2 + m * 16);
        zr[m] = xr[a]; zi[m] = xi[a];
    }
    fft16<INV>(zr, zi);
    #pragma unroll
    for (int j = 1; j < 16; ++j)
        cmul_tw<INV>(twr, twi, (tid & 15) * 16 * j, zr[j], zi[j]);
    #pragma unroll
    for (int j = 0; j < 16; ++j) {
        const int a = SLOT2(base2 + j * 16);
        xr[a] = zr[j]; xi[a] = zi[j];
    }
    __syncthreads();
    // ---- pass 3: k1 = t>>4, j1 = t&15; FFT16 over m2 (contiguous 16)
    const int base3 = (tid >> 4) * 256 + (tid & 15) * 16;
    #pragma unroll
    for (int m = 0; m < 16; m += 2) {
        const int a = SLOT2(base3 + m);       // pad constant over the 16-run
        const float2 vr = *(const float2*)&xr[a];
        const float2 vi = *(const float2*)&xi[a];
        zr[m] = vr.x; zr[m + 1] = vr.y;
        zi[m] = vi.x; zi[m + 1] = vi.y;
    }
    fft16<INV>(zr, zi);
    __syncthreads();   // all pass-3 reads complete before scattered writes
    const int ob = (tid >> 4) + (tid & 15) * 16;
    #pragma unroll
    for (int j2 = 0; j2 < 16; ++j2) {
        const int a = SLOT2(ob + j2 * 256);
        xr[a] = zr[j2]; xi[a] = zi[j2];
    }
    __syncthreads();
}

// store: Z = FFT(k + i*v); FFT(k)*FFT(v) = (Z[f]^2 - conj(Z[-f])^2)/(4i); sum over pairs.
__global__ __launch_bounds__(256) void store_kernel(
    const float* __restrict__ keys, const float* __restrict__ values,
    float* __restrict__ Mre, float* __restrict__ Mim) {
    __shared__ float xr[4352], xi[4352], twr[1024], twi[1024];
    const int tid = (int)threadIdx.x;
    init_twiddle(twr, twi, tid);

    float mr[16], mi[16];
    #pragma unroll
    for (int r = 0; r < 16; ++r) { mr[r] = 0.f; mi[r] = 0.f; }

    const int pair0 = (int)blockIdx.x * PPB;
    float4 ka[4], va[4];
    {
        const float* kp = keys + (size_t)pair0 * DD;
        const float* vp = values + (size_t)pair0 * DD;
        #pragma unroll
        for (int q = 0; q < 4; ++q) {
            ka[q] = ((const float4*)kp)[tid + 256 * q];
            va[q] = ((const float4*)vp)[tid + 256 * q];
        }
    }

    for (int p = 0; p < PPB; ++p) {
        __syncthreads();   // prev epilogue reads done; twiddles visible (p=0)
        #pragma unroll
        for (int q = 0; q < 4; ++q) {
            const int j = (tid + 256 * q) * 4;
            const int a = SLOT2(j);            // pad constant over j..j+3
            *(float2*)&xr[a]     = make_float2(ka[q].x, ka[q].y);
            *(float2*)&xr[a + 2] = make_float2(ka[q].z, ka[q].w);
            *(float2*)&xi[a]     = make_float2(va[q].x, va[q].y);
            *(float2*)&xi[a + 2] = make_float2(va[q].z, va[q].w);
        }
        if (p + 1 < PPB) {                     // prefetch next pair (hidden under FFT)
            const float* kp = keys + (size_t)(pair0 + p + 1) * DD;
            const float* vp = values + (size_t)(pair0 + p + 1) * DD;
            #pragma unroll
            for (int q = 0; q < 4; ++q) {
                ka[q] = ((const float4*)kp)[tid + 256 * q];
                va[q] = ((const float4*)vp)[tid + 256 * q];
            }
        }
        __syncthreads();
        fft4096r<0>(xr, xi, twr, twi, tid);
        #pragma unroll
        for (int r = 0; r < 16; ++r) {
            const int f = tid + 256 * r;
            const int fn = (DD - f) & (DD - 1);
            const float ar = xr[SLOT2(f)],  ai = xi[SLOT2(f)];
            const float br = xr[SLOT2(fn)], bi = xi[SLOT2(fn)];
            const float a2r = ar * ar - ai * ai, a2i = 2.f * ar * ai;
            const float c2r = br * br - bi * bi, c2i = -2.f * br * bi;
            mr[r] += 0.25f * (a2i - c2i);
            mi[r] -= 0.25f * (a2r - c2r);
        }
    }
    #pragma unroll
    for (int r = 0; r < 16; ++r) {
        const int f = tid + 256 * r;
        atomicAdd(&Mre[f], mr[r]);
        atomicAdd(&Mim[f], mi[r]);
    }
}

// retrieve: Z = FFT(q0 + i*q1); W[f] = FM[f] * Z[(-f) mod N]; IFFT(W) = row0 + i*row1.
__global__ __launch_bounds__(256) void retrieve_kernel(
    const float* __restrict__ queries, const float* __restrict__ Mre,
    const float* __restrict__ Mim, float* __restrict__ out) {
    __shared__ float xr[4352], xi[4352], twr[1024], twi[1024];
    const int tid = (int)threadIdx.x;
    init_twiddle(twr, twi, tid);

    const int q0 = (int)blockIdx.x * 2, q1 = q0 + 1;
    {
        const float* r0 = queries + (size_t)q0 * DD;
        const float* r1 = queries + (size_t)q1 * DD;
        #pragma unroll
        for (int q = 0; q < 4; ++q) {
            const float4 a = ((const float4*)r0)[tid + 256 * q];
            const float4 b = ((const float4*)r1)[tid + 256 * q];
            const int j = (tid + 256 * q) * 4;
            const int s = SLOT2(j);
            *(float2*)&xr[s]     = make_float2(a.x, a.y);
            *(float2*)&xr[s + 2] = make_float2(a.z, a.w);
            *(float2*)&xi[s]     = make_float2(b.x, b.y);
            *(float2*)&xi[s + 2] = make_float2(b.z, b.w);
        }
    }
    __syncthreads();   // scatter + twiddles visible
    fft4096r<0>(xr, xi, twr, twi, tid);

    // W build: read Z mirrors + FM into regs, sync, overwrite in place
    float zmr[16], zmi[16], fmr[16], fmi[16];
    #pragma unroll
    for (int r = 0; r < 16; ++r) {
        const int f = tid + 256 * r;
        const int fn = (DD - f) & (DD - 1);
        zmr[r] = xr[SLOT2(fn)]; zmi[r] = xi[SLOT2(fn)];
        fmr[r] = Mre[f];        fmi[r] = Mim[f];
    }
    __syncthreads();
    #pragma unroll
    for (int r = 0; r < 16; ++r) {
        const int f = tid + 256 * r;
        const int a = SLOT2(f);
        xr[a] = fmr[r] * zmr[r] - fmi[r] * zmi[r];
        xi[a] = fmr[r] * zmi[r] + fmi[r] * zmr[r];
    }
    __syncthreads();
    fft4096r<1>(xr, xi, twr, twi, tid);

    const float sc = 1.f / 4096.f;
    float* o0 = out + (size_t)q0 * DD;
    float* o1 = out + (size_t)q1 * DD;
    #pragma unroll
    for (int q = 0; q < 4; ++q) {
        const int j = (tid + 256 * q) * 4;
        const int a = SLOT2(j);
        const float2 r01 = *(const float2*)&xr[a];
        const float2 r23 = *(const float2*)&xr[a + 2];
        const float2 i01 = *(const float2*)&xi[a];
        const float2 i23 = *(const float2*)&xi[a + 2];
        float4 v0, v1;
        v0.x = r01.x * sc; v0.y = r01.y * sc; v0.z = r23.x * sc; v0.w = r23.y * sc;
        v1.x = i01.x * sc; v1.y = i01.y * sc; v1.z = i23.x * sc; v1.w = i23.y * sc;
        ((float4*)o0)[tid + 256 * q] = v0;
        ((float4*)o1)[tid + 256 * q] = v1;
    }
}

extern "C" void kernel_launch(void* const* d_in, const int* in_sizes, int n_in,
                              void* d_out, int out_size, void* d_ws, size_t ws_size,
                              hipStream_t stream) {
    const float* keys    = (const float*)d_in[0];
    const float* values  = (const float*)d_in[1];
    const float* queries = (const float*)d_in[2];
    float* out = (float*)d_out;
    char* ws = (char*)d_ws;

    float* Mre = (float*)ws;               // 16KB
    float* Mim = (float*)(ws + 16384);     // 16KB

    hipMemsetAsync(Mre, 0, 2 * DD * sizeof(float), stream);

    store_kernel<<<NPAIR / PPB, 256, 0, stream>>>(keys, values, Mre, Mim);
    retrieve_kernel<<<NQUERY / 2, 256, 0, stream>>>(queries, Mre, Mim, out);
}

// Round 6
// 107.361 us; speedup vs baseline: 4.1576x; 1.4330x over previous
//
#include <hip/hip_runtime.h>
#include <stdint.h>

#define DD 4096
#define NPAIR 4096
#define NQUERY 4096
#define PPB 8

// padded LDS slot: +2 floats per 32-float block; keeps float2 alignment,
// <=2-way conflicts on all pass access patterns (analyzed per pass).
#define SLOT2(i) ((i) + ((((i) >> 5)) << 1))

// in-register 16-point DFT: z[n] -> z[k], natural order both sides.
// Internally n = 4*n1 + n2, k = k1 + 4*k2 (four-step, A=B=4).
template <int INV>
static __device__ __forceinline__ void fft16(float* zr, float* zi) {
    const float K1 = 0.92387953251128674f;   // cos(pi/8)
    const float S1 = 0.38268343236508978f;   // sin(pi/8)
    const float C2 = 0.70710678118654752f;
    float gr[16], gi[16];                    // g[k1*4 + n2]
    #pragma unroll
    for (int n2 = 0; n2 < 4; ++n2) {
        const float x0r = zr[n2],      x0i = zi[n2];
        const float x1r = zr[4 + n2],  x1i = zi[4 + n2];
        const float x2r = zr[8 + n2],  x2i = zi[8 + n2];
        const float x3r = zr[12 + n2], x3i = zi[12 + n2];
        const float s02r = x0r + x2r, s02i = x0i + x2i;
        const float d02r = x0r - x2r, d02i = x0i - x2i;
        const float s13r = x1r + x3r, s13i = x1i + x3i;
        const float d13r = x1r - x3r, d13i = x1i - x3i;
        gr[0 * 4 + n2] = s02r + s13r; gi[0 * 4 + n2] = s02i + s13i;
        gr[2 * 4 + n2] = s02r - s13r; gi[2 * 4 + n2] = s02i - s13i;
        if (!INV) {
            gr[1 * 4 + n2] = d02r + d13i; gi[1 * 4 + n2] = d02i - d13r;
            gr[3 * 4 + n2] = d02r - d13i; gi[3 * 4 + n2] = d02i + d13r;
        } else {
            gr[1 * 4 + n2] = d02r - d13i; gi[1 * 4 + n2] = d02i + d13r;
            gr[3 * 4 + n2] = d02r + d13i; gi[3 * 4 + n2] = d02i - d13r;
        }
    }
    // twiddle w16^{n2*k1} (forward values; INV conjugates)
#define TW16(K, N, WR, WI) do {                                              \
        const float wr_ = (WR), wi_ = INV ? -(WI) : (WI);                    \
        const float xr_ = gr[(K) * 4 + (N)], xi_ = gi[(K) * 4 + (N)];        \
        gr[(K) * 4 + (N)] = xr_ * wr_ - xi_ * wi_;                           \
        gi[(K) * 4 + (N)] = xr_ * wi_ + xi_ * wr_; } while (0)
    TW16(1, 1, K1, -S1);  TW16(1, 2, C2, -C2);   TW16(1, 3, S1, -K1);
    TW16(2, 1, C2, -C2);  TW16(2, 2, 0.f, -1.f); TW16(2, 3, -C2, -C2);
    TW16(3, 1, S1, -K1);  TW16(3, 2, -C2, -C2);  TW16(3, 3, -K1, S1);
#undef TW16
    #pragma unroll
    for (int k1 = 0; k1 < 4; ++k1) {
        const float x0r = gr[k1 * 4 + 0], x0i = gi[k1 * 4 + 0];
        const float x1r = gr[k1 * 4 + 1], x1i = gi[k1 * 4 + 1];
        const float x2r = gr[k1 * 4 + 2], x2i = gi[k1 * 4 + 2];
        const float x3r = gr[k1 * 4 + 3], x3i = gi[k1 * 4 + 3];
        const float s02r = x0r + x2r, s02i = x0i + x2i;
        const float d02r = x0r - x2r, d02i = x0i - x2i;
        const float s13r = x1r + x3r, s13i = x1i + x3i;
        const float d13r = x1r - x3r, d13i = x1i - x3i;
        zr[k1]      = s02r + s13r; zi[k1]      = s02i + s13i;
        zr[k1 + 8]  = s02r - s13r; zi[k1 + 8]  = s02i - s13i;
        if (!INV) {
            zr[k1 + 4]  = d02r + d13i; zi[k1 + 4]  = d02i - d13r;
            zr[k1 + 12] = d02r - d13i; zi[k1 + 12] = d02i + d13r;
        } else {
            zr[k1 + 4]  = d02r - d13i; zi[k1 + 4]  = d02i + d13r;
            zr[k1 + 12] = d02r + d13i; zi[k1 + 12] = d02i - d13r;
        }
    }
}

// z[k] *= base^k for k=1..15 (chained powers, 2 live regs, no LDS)
static __device__ __forceinline__ void twiddle_chain(float* zr, float* zi,
                                                     float br, float bi) {
    float cr = br, ci = bi;
    #pragma unroll
    for (int k = 1; k < 16; ++k) {
        const float xr = zr[k], xi = zi[k];
        zr[k] = xr * cr - xi * ci;
        zi[k] = xr * ci + xi * cr;
        if (k < 15) {
            const float nr = cr * br - ci * bi;
            const float ni = cr * bi + ci * br;
            cr = nr; ci = ni;
        }
    }
}

// 4096-pt FFT, natural-order in/out in padded LDS arrays xr/xi.
// Four-step: 4096 = 16 x 16 x 16; 3 register-FFT16 passes, 2 LDS transposes.
// b1 = w4096^tid, b2 = w4096^(16*(tid&15)) -- caller passes CONJUGATED bases
// for the inverse transform. Caller syncs before; ends with sync.
template <int INV>
static __device__ void fft4096r(float* xr, float* xi,
                                float b1r, float b1i, float b2r, float b2i,
                                int tid) {
    float zr[16], zi[16];
    // ---- pass 1: thread t = n2 in [0,256); FFT16 over n1 (stride 256)
    #pragma unroll
    for (int n = 0; n < 16; ++n) {
        const int a = SLOT2(n * 256 + tid);
        zr[n] = xr[a]; zi[n] = xi[a];
    }
    fft16<INV>(zr, zi);
    twiddle_chain(zr, zi, b1r, b1i);
    #pragma unroll
    for (int k = 0; k < 16; ++k) {
        const int a = SLOT2(k * 256 + tid);
        xr[a] = zr[k]; xi[a] = zi[k];
    }
    __syncthreads();
    // ---- pass 2: k1 = t>>4, m2 = t&15; FFT16 over m1 (stride 16)
    const int base2 = (tid >> 4) * 256 + (tid & 15);
    #pragma unroll
    for (int m = 0; m < 16; ++m) {
        const int a = SLOT2(base2 + m * 16);
        zr[m] = xr[a]; zi[m] = xi[a];
    }
    fft16<INV>(zr, zi);
    twiddle_chain(zr, zi, b2r, b2i);
    #pragma unroll
    for (int j = 0; j < 16; ++j) {
        const int a = SLOT2(base2 + j * 16);
        xr[a] = zr[j]; xi[a] = zi[j];
    }
    __syncthreads();
    // ---- pass 3: k1 = t>>4, j1 = t&15; FFT16 over m2 (contiguous 16)
    const int base3 = (tid >> 4) * 256 + (tid & 15) * 16;
    #pragma unroll
    for (int m = 0; m < 16; m += 2) {
        const int a = SLOT2(base3 + m);       // pad constant over the 16-run
        const float2 vr = *(const float2*)&xr[a];
        const float2 vi = *(const float2*)&xi[a];
        zr[m] = vr.x; zr[m + 1] = vr.y;
        zi[m] = vi.x; zi[m + 1] = vi.y;
    }
    fft16<INV>(zr, zi);
    __syncthreads();   // all pass-3 reads complete before scattered writes
    const int ob = (tid >> 4) + (tid & 15) * 16;
    #pragma unroll
    for (int j2 = 0; j2 < 16; ++j2) {
        const int a = SLOT2(ob + j2 * 256);
        xr[a] = zr[j2]; xi[a] = zi[j2];
    }
    __syncthreads();
}

// store: Z = FFT(k + i*v); FFT(k)*FFT(v) = (Z[f]^2 - conj(Z[-f])^2)/(4i); sum over pairs.
__global__ __launch_bounds__(256) void store_kernel(
    const float* __restrict__ keys, const float* __restrict__ values,
    float* __restrict__ Mre, float* __restrict__ Mim) {
    __shared__ float xr[4352], xi[4352];
    const int tid = (int)threadIdx.x;

    float b1r, b1i, b2r, b2i;
    {
        const float a1 = -6.2831853071795864769f * (float)tid / 4096.f;
        const float a2 = -6.2831853071795864769f * (float)(tid & 15) / 256.f;
        sincosf(a1, &b1i, &b1r);
        sincosf(a2, &b2i, &b2r);
    }

    float mr[16], mi[16];
    #pragma unroll
    for (int r = 0; r < 16; ++r) { mr[r] = 0.f; mi[r] = 0.f; }

    const int pair0 = (int)blockIdx.x * PPB;
    float4 ka[4], va[4];
    {
        const float* kp = keys + (size_t)pair0 * DD;
        const float* vp = values + (size_t)pair0 * DD;
        #pragma unroll
        for (int q = 0; q < 4; ++q) {
            ka[q] = ((const float4*)kp)[tid + 256 * q];
            va[q] = ((const float4*)vp)[tid + 256 * q];
        }
    }

    for (int p = 0; p < PPB; ++p) {
        __syncthreads();   // prev epilogue reads done
        #pragma unroll
        for (int q = 0; q < 4; ++q) {
            const int j = (tid + 256 * q) * 4;
            const int a = SLOT2(j);            // pad constant over j..j+3
            *(float2*)&xr[a]     = make_float2(ka[q].x, ka[q].y);
            *(float2*)&xr[a + 2] = make_float2(ka[q].z, ka[q].w);
            *(float2*)&xi[a]     = make_float2(va[q].x, va[q].y);
            *(float2*)&xi[a + 2] = make_float2(va[q].z, va[q].w);
        }
        if (p + 1 < PPB) {                     // prefetch next pair (hidden under FFT)
            const float* kp = keys + (size_t)(pair0 + p + 1) * DD;
            const float* vp = values + (size_t)(pair0 + p + 1) * DD;
            #pragma unroll
            for (int q = 0; q < 4; ++q) {
                ka[q] = ((const float4*)kp)[tid + 256 * q];
                va[q] = ((const float4*)vp)[tid + 256 * q];
            }
        }
        __syncthreads();
        fft4096r<0>(xr, xi, b1r, b1i, b2r, b2i, tid);
        #pragma unroll
        for (int r = 0; r < 16; ++r) {
            const int f = tid + 256 * r;
            const int fn = (DD - f) & (DD - 1);
            const float ar = xr[SLOT2(f)],  ai = xi[SLOT2(f)];
            const float br = xr[SLOT2(fn)], bi = xi[SLOT2(fn)];
            const float a2r = ar * ar - ai * ai, a2i = 2.f * ar * ai;
            const float c2r = br * br - bi * bi, c2i = -2.f * br * bi;
            mr[r] += 0.25f * (a2i - c2i);
            mi[r] -= 0.25f * (a2r - c2r);
        }
    }
    #pragma unroll
    for (int r = 0; r < 16; ++r) {
        const int f = tid + 256 * r;
        atomicAdd(&Mre[f], mr[r]);
        atomicAdd(&Mim[f], mi[r]);
    }
}

// retrieve: Z = FFT(q0 + i*q1); W[f] = FM[f] * Z[(-f) mod N]; IFFT(W) = row0 + i*row1.
__global__ __launch_bounds__(256) void retrieve_kernel(
    const float* __restrict__ queries, const float* __restrict__ Mre,
    const float* __restrict__ Mim, float* __restrict__ out) {
    __shared__ float xr[4352], xi[4352];
    const int tid = (int)threadIdx.x;

    float b1r, b1i, b2r, b2i;
    {
        const float a1 = -6.2831853071795864769f * (float)tid / 4096.f;
        const float a2 = -6.2831853071795864769f * (float)(tid & 15) / 256.f;
        sincosf(a1, &b1i, &b1r);
        sincosf(a2, &b2i, &b2r);
    }

    const int q0 = (int)blockIdx.x * 2, q1 = q0 + 1;
    {
        const float* r0 = queries + (size_t)q0 * DD;
        const float* r1 = queries + (size_t)q1 * DD;
        #pragma unroll
        for (int q = 0; q < 4; ++q) {
            const float4 a = ((const float4*)r0)[tid + 256 * q];
            const float4 b = ((const float4*)r1)[tid + 256 * q];
            const int j = (tid + 256 * q) * 4;
            const int s = SLOT2(j);
            *(float2*)&xr[s]     = make_float2(a.x, a.y);
            *(float2*)&xr[s + 2] = make_float2(a.z, a.w);
            *(float2*)&xi[s]     = make_float2(b.x, b.y);
            *(float2*)&xi[s + 2] = make_float2(b.z, b.w);
        }
    }
    __syncthreads();
    fft4096r<0>(xr, xi, b1r, b1i, b2r, b2i, tid);

    // W build: read Z mirrors + FM into regs, sync, overwrite in place
    float zmr[16], zmi[16], fmr[16], fmi[16];
    #pragma unroll
    for (int r = 0; r < 16; ++r) {
        const int f = tid + 256 * r;
        const int fn = (DD - f) & (DD - 1);
        zmr[r] = xr[SLOT2(fn)]; zmi[r] = xi[SLOT2(fn)];
        fmr[r] = Mre[f];        fmi[r] = Mim[f];
    }
    __syncthreads();
    #pragma unroll
    for (int r = 0; r < 16; ++r) {
        const int f = tid + 256 * r;
        const int a = SLOT2(f);
        xr[a] = fmr[r] * zmr[r] - fmi[r] * zmi[r];
        xi[a] = fmr[r] * zmi[r] + fmi[r] * zmr[r];
    }
    __syncthreads();
    fft4096r<1>(xr, xi, b1r, -b1i, b2r, -b2i, tid);

    const float sc = 1.f / 4096.f;
    float* o0 = out + (size_t)q0 * DD;
    float* o1 = out + (size_t)q1 * DD;
    #pragma unroll
    for (int q = 0; q < 4; ++q) {
        const int j = (tid + 256 * q) * 4;
        const int a = SLOT2(j);
        const float2 r01 = *(const float2*)&xr[a];
        const float2 r23 = *(const float2*)&xr[a + 2];
        const float2 i01 = *(const float2*)&xi[a];
        const float2 i23 = *(const float2*)&xi[a + 2];
        float4 v0, v1;
        v0.x = r01.x * sc; v0.y = r01.y * sc; v0.z = r23.x * sc; v0.w = r23.y * sc;
        v1.x = i01.x * sc; v1.y = i01.y * sc; v1.z = i23.x * sc; v1.w = i23.y * sc;
        ((float4*)o0)[tid + 256 * q] = v0;
        ((float4*)o1)[tid + 256 * q] = v1;
    }
}

extern "C" void kernel_launch(void* const* d_in, const int* in_sizes, int n_in,
                              void* d_out, int out_size, void* d_ws, size_t ws_size,
                              hipStream_t stream) {
    const float* keys    = (const float*)d_in[0];
    const float* values  = (const float*)d_in[1];
    const float* queries = (const float*)d_in[2];
    float* out = (float*)d_out;
    char* ws = (char*)d_ws;

    float* Mre = (float*)ws;               // 16KB
    float* Mim = (float*)(ws + 16384);     // 16KB

    hipMemsetAsync(Mre, 0, 2 * DD * sizeof(float), stream);

    store_kernel<<<NPAIR / PPB, 256, 0, stream>>>(keys, values, Mre, Mim);
    retrieve_kernel<<<NQUERY / 2, 256, 0, stream>>>(queries, Mre, Mim, out);
}